// Round 10
// baseline (97.446 us; speedup 1.0000x reference)
//
#include <hip/hip_runtime.h>

// ============================================================================
// r10: r9 semantics (verified: directed pairs, rev-first interleave) +
// packed-atom table. Prologue kernel packs (x,y,z,species_bits) per atom into
// d_ws as 16B-aligned float4 -> main kernel does ONE dwordx4 load per pair
// (VMEM loads 17 -> 5 per thread; TA-pipe issue time ~10us -> ~5us/CU).
// Same-stream launches serialize => graph-capture safe. ws<256KB -> r9 path.
// ============================================================================

namespace r10 {

constexpr int kM = 8;
constexpr int kN = 2048;
constexpr int kAtoms = kM * kN;             // 16,384
constexpr int kPPM = kN * (kN - 1) / 2;     // 2,096,128 triu pairs per molecule
constexpr int kP   = kPPM * kM;             // 16,769,024 triu pairs total
constexpr long long E = 2LL * kP;           // 33,538,048 directed pairs

typedef __attribute__((ext_vector_type(8))) unsigned short u16x8;
typedef __attribute__((ext_vector_type(4))) float f32x4;

__device__ __forceinline__ unsigned short f2bf(float f) {
    unsigned int u = __float_as_uint(f);
    u += 0x7FFFu + ((u >> 16) & 1u);        // round-to-nearest-even
    return (unsigned short)(u >> 16);
}

__device__ __forceinline__ int row_off(int i) {
    return (i * (2 * kN - 1 - i)) >> 1;
}

// -------- prologue: pack (x,y,z,species_bits) into 16B records --------------
__global__ __launch_bounds__(256)
void pack_atoms(const int* __restrict__ species,
                const float* __restrict__ coords,
                f32x4* __restrict__ xyzs)
{
    const int a = blockIdx.x * 256 + threadIdx.x;
    if (a >= kAtoms) return;
    f32x4 v;
    v.x = coords[3 * a + 0];
    v.y = coords[3 * a + 1];
    v.z = coords[3 * a + 2];
    v.w = __int_as_float(species[a]);
    xyzs[a] = v;
}

// -------- main kernel, packed-table path ------------------------------------
__global__ __launch_bounds__(256)
void fp_r10(const f32x4* __restrict__ xyzs,
            const int* __restrict__ cutw,
            unsigned short* __restrict__ out)
{
#pragma clang fp contract(off)
    const int g = blockIdx.x * 256 + threadIdx.x;   // group of 4 triu ranks
    const int t0 = g * 4;
    if (t0 >= kP) return;

    const int m = t0 / kPPM;                // 4 | kPPM -> group never crosses mol
    const int r0 = t0 - m * kPPM;

    // invert triangular index (4095^2 = 16,769,025 exact in f32)
    const float s = (float)(16769025 - 8 * r0);
    int i = (int)floorf((4095.0f - sqrtf(s)) * 0.5f);
    i = min(max(i, 0), kN - 2);
    while (row_off(i) > r0) --i;
    while (row_off(i + 1) <= r0) ++i;
    int j = i + 1 + (r0 - row_off(i));

    // cutoff: robust decode (int32 / int64-low-word / float32)
    const int w0 = cutw[0];
    const float cutoff = (w0 > 0 && w0 < (1 << 20)) ? (float)w0 : __int_as_float(w0);

    const int base = m * kN;

    // hoisted i-atom record (reloaded only on row wrap, ~0.4% of groups)
    int a = base + i;
    f32x4 wa = xyzs[a];
    unsigned short ba = f2bf((float)a);

    u16x8 vi0, vi1, vd, vv;
    u16x8 vf0, vf1, vf2;
    unsigned short df[24];

#pragma unroll
    for (int k = 0; k < 4; ++k) {
        const int b = base + j;
        const f32x4 wb = xyzs[b];           // one dwordx4: x,y,z,species_bits

        const float dx = wa.x - wb.x;
        const float dy = wa.y - wb.y;
        const float dz = wa.z - wb.z;
        const float d2 = dx * dx + dy * dy + dz * dz;   // no FMA: match np
        const float dist = sqrtf(d2);

        const bool dummy = (__float_as_int(wa.w) == -1) || (__float_as_int(wb.w) == -1);
        const bool valid = (dist <= cutoff) && !dummy;

        const unsigned short bb = f2bf((float)b);
        const unsigned short bd = valid ? f2bf(dist) : (unsigned short)0;
        const unsigned short bv = valid ? (unsigned short)0x3F80 : (unsigned short)0;
        const unsigned short fx = valid ? f2bf(dx) : (unsigned short)0;   // fwd (i,j)
        const unsigned short fy = valid ? f2bf(dy) : (unsigned short)0;
        const unsigned short fz = valid ? f2bf(dz) : (unsigned short)0;
        const unsigned short gx = valid ? (unsigned short)(fx ^ 0x8000) : (unsigned short)0;
        const unsigned short gy = valid ? (unsigned short)(fy ^ 0x8000) : (unsigned short)0;
        const unsigned short gz = valid ? (unsigned short)(fz ^ 0x8000) : (unsigned short)0;

        // REV first (slot 2k): (j,i), diff = -(fwd); FWD second (slot 2k+1)
        vi0[2 * k]     = bb;  vi0[2 * k + 1] = ba;
        vi1[2 * k]     = ba;  vi1[2 * k + 1] = bb;
        vd[2 * k]      = bd;  vd[2 * k + 1]  = bd;
        vv[2 * k]      = bv;  vv[2 * k + 1]  = bv;
        df[6 * k + 0] = gx;  df[6 * k + 1] = gy;  df[6 * k + 2] = gz;
        df[6 * k + 3] = fx;  df[6 * k + 4] = fy;  df[6 * k + 5] = fz;

        // advance; reload hoisted i-record on row wrap
        ++j;
        if (j == kN) {
            ++i; j = i + 1;
            if (k < 3) {
                a = base + i;
                wa = xyzs[a];
                ba = f2bf((float)a);
            }
        }
    }

#pragma unroll
    for (int e = 0; e < 8; ++e) {
        vf0[e] = df[e];
        vf1[e] = df[8 + e];
        vf2[e] = df[16 + e];
    }

    // 16B-aligned plain vector stores
    *((u16x8*)(out) + g)             = vi0;   // idx0
    *((u16x8*)(out + E) + g)         = vi1;   // idx1
    *((u16x8*)(out + 2 * E) + g)     = vd;    // dist
    u16x8* dfp = (u16x8*)(out + 3 * E) + 3 * g;   // diff
    dfp[0] = vf0; dfp[1] = vf1; dfp[2] = vf2;
    *((u16x8*)(out + 6 * E) + g)     = vv;    // valid
}

// -------- fallback (r9, verified) if ws too small ---------------------------
__global__ __launch_bounds__(256)
void fp_r10_fb(const int* __restrict__ species,
               const float* __restrict__ coords,
               const int* __restrict__ cutw,
               unsigned short* __restrict__ out)
{
#pragma clang fp contract(off)
    const int g = blockIdx.x * 256 + threadIdx.x;
    const int t0 = g * 4;
    if (t0 >= kP) return;

    const int m = t0 / kPPM;
    const int r0 = t0 - m * kPPM;

    const float s = (float)(16769025 - 8 * r0);
    int i = (int)floorf((4095.0f - sqrtf(s)) * 0.5f);
    i = min(max(i, 0), kN - 2);
    while (row_off(i) > r0) --i;
    while (row_off(i + 1) <= r0) ++i;
    int j = i + 1 + (r0 - row_off(i));

    const int w0 = cutw[0];
    const float cutoff = (w0 > 0 && w0 < (1 << 20)) ? (float)w0 : __int_as_float(w0);

    const int base = m * kN;

    int a = base + i;
    float ax = coords[3 * a + 0], ay = coords[3 * a + 1], az = coords[3 * a + 2];
    int   sa = species[a];
    unsigned short ba = f2bf((float)a);

    u16x8 vi0, vi1, vd, vv;
    u16x8 vf0, vf1, vf2;
    unsigned short df[24];

#pragma unroll
    for (int k = 0; k < 4; ++k) {
        const int b = base + j;
        const float bx = coords[3 * b + 0], by = coords[3 * b + 1], bz = coords[3 * b + 2];
        const int   sb = species[b];

        const float dx = ax - bx;
        const float dy = ay - by;
        const float dz = az - bz;
        const float d2 = dx * dx + dy * dy + dz * dz;
        const float dist = sqrtf(d2);

        const bool dummy = (sa == -1) || (sb == -1);
        const bool valid = (dist <= cutoff) && !dummy;

        const unsigned short bb = f2bf((float)b);
        const unsigned short bd = valid ? f2bf(dist) : (unsigned short)0;
        const unsigned short bv = valid ? (unsigned short)0x3F80 : (unsigned short)0;
        const unsigned short fx = valid ? f2bf(dx) : (unsigned short)0;
        const unsigned short fy = valid ? f2bf(dy) : (unsigned short)0;
        const unsigned short fz = valid ? f2bf(dz) : (unsigned short)0;
        const unsigned short gx = valid ? (unsigned short)(fx ^ 0x8000) : (unsigned short)0;
        const unsigned short gy = valid ? (unsigned short)(fy ^ 0x8000) : (unsigned short)0;
        const unsigned short gz = valid ? (unsigned short)(fz ^ 0x8000) : (unsigned short)0;

        vi0[2 * k]     = bb;  vi0[2 * k + 1] = ba;
        vi1[2 * k]     = ba;  vi1[2 * k + 1] = bb;
        vd[2 * k]      = bd;  vd[2 * k + 1]  = bd;
        vv[2 * k]      = bv;  vv[2 * k + 1]  = bv;
        df[6 * k + 0] = gx;  df[6 * k + 1] = gy;  df[6 * k + 2] = gz;
        df[6 * k + 3] = fx;  df[6 * k + 4] = fy;  df[6 * k + 5] = fz;

        ++j;
        if (j == kN) {
            ++i; j = i + 1;
            if (k < 3) {
                a = base + i;
                ax = coords[3 * a + 0]; ay = coords[3 * a + 1]; az = coords[3 * a + 2];
                sa = species[a];
                ba = f2bf((float)a);
            }
        }
    }

#pragma unroll
    for (int e = 0; e < 8; ++e) {
        vf0[e] = df[e];
        vf1[e] = df[8 + e];
        vf2[e] = df[16 + e];
    }

    *((u16x8*)(out) + g)             = vi0;
    *((u16x8*)(out + E) + g)         = vi1;
    *((u16x8*)(out + 2 * E) + g)     = vd;
    u16x8* dfp = (u16x8*)(out + 3 * E) + 3 * g;
    dfp[0] = vf0; dfp[1] = vf1; dfp[2] = vf2;
    *((u16x8*)(out + 6 * E) + g)     = vv;
}

} // namespace r10

extern "C" void kernel_launch(void* const* d_in, const int* in_sizes, int n_in,
                              void* d_out, int out_size, void* d_ws, size_t ws_size,
                              hipStream_t stream) {
    using namespace r10;
    const int*   species = (const int*)d_in[0];
    const float* coords  = (const float*)d_in[1];
    const int*   cutoff  = (const int*)d_in[2];
    unsigned short* out  = (unsigned short*)d_out;

    const int groups = kP / 4;                   // 4,192,256
    const int blocks = groups / 256;             // 16,376 exact

    if (ws_size >= (size_t)kAtoms * 16) {
        f32x4* xyzs = (f32x4*)d_ws;
        pack_atoms<<<(kAtoms + 255) / 256, 256, 0, stream>>>(species, coords, xyzs);
        fp_r10<<<blocks, 256, 0, stream>>>(xyzs, cutoff, out);
    } else {
        fp_r10_fb<<<blocks, 256, 0, stream>>>(species, coords, cutoff, out);
    }
}